// Round 5
// baseline (320.981 us; speedup 1.0000x reference)
//
#include <hip/hip_runtime.h>
#include <stdint.h>

#define N_NODES 3072
#define D_IN    256
#define HIDDEN  384
#define HEADS   6
#define NH1     64
#define C1      1152   // 3*HIDDEN
#define C2      768    // 3*D_IN
#define MASK_ULL   48  // 3072/64 per row
#define MASK_BYTES 384 // 3072/8 per row
#define MASK_BSTRIDE ((size_t)N_NODES * MASK_BYTES)  // per-branch mask stride (bytes)
#define QS      4      // j-splits for the sent branch (sect/doc get 1)
#define LOG2E   1.4426950408889634f

typedef __bf16 bf16;
typedef __bf16 bf16x8 __attribute__((ext_vector_type(8)));
typedef __bf16 bf16x4 __attribute__((ext_vector_type(4)));
typedef float  f32x4  __attribute__((ext_vector_type(4)));

__device__ __forceinline__ void atomAddF(float* p, float v) {
  __hip_atomic_fetch_add(p, v, __ATOMIC_RELAXED, __HIP_MEMORY_SCOPE_AGENT);
}
__device__ __forceinline__ float fexp2(float x) {   // D = 2^S0
  float r; asm("v_exp_f32 %0, %1" : "=v"(r) : "v"(x)); return r;
}
// 32-aligned chunk boundary: q in [0,Qb]; B(0) floors jlo, B(Qb) ceils jhi.
__device__ __forceinline__ int bnd32(int jlo, int jhi, int len, int q, int Qb) {
  return (q >= Qb) ? ((jhi + 31) & ~31) : ((jlo + (len * q) / Qb) & ~31);
}

// ---------------------------------------------------------------- cast fp32->bf16
struct CastArgs {
  const float* src[11];
  bf16*        dst[11];
  int          cum4[12];
};

__global__ __launch_bounds__(256) void cast_all_kernel(CastArgs A) {
  int g = blockIdx.x * 256 + threadIdx.x;
  int j = 0;
#pragma unroll
  for (int k = 1; k < 11; ++k) j += (g >= A.cum4[k]);
  int e = (g - A.cum4[j]) * 4;
  float4 v = *(const float4*)(A.src[j] + e);
  bf16x4 o = { (bf16)v.x, (bf16)v.y, (bf16)v.z, (bf16)v.w };
  *(bf16x4*)(A.dst[j] + e) = o;
}

// ---------------------------------------------------------------- adj -> 3 per-branch bitmasks (range folded in)
__global__ __launch_bounds__(256) void pack_adj_kernel(const int* __restrict__ adj,
                                                       unsigned long long* __restrict__ maskU,
                                                       const int* __restrict__ dnum,
                                                       const int* __restrict__ snum) {
  int dn = dnum[0], sn = snum[0];
  int bb1 = N_NODES - sn - dn, bb2 = N_NODES - dn;
  int row = blockIdx.x;
  const int* ar = adj + (size_t)row * N_NODES;
  int lane = threadIdx.x & 63, wave = threadIdx.x >> 6;
#pragma unroll
  for (int it = 0; it < N_NODES / 256; ++it) {
    int j = it * 256 + wave * 64 + lane;
    bool a = ar[j] != 0;
    unsigned long long m0 = __ballot(a && (j < bb1));
    unsigned long long m1 = __ballot(a && (j >= bb1) && (j < bb2));
    unsigned long long m2 = __ballot(a && (j >= bb2));
    if (lane == 0) {
      size_t o = (size_t)row * MASK_ULL + it * 4 + wave;
      maskU[o] = m0;
      maskU[o + (size_t)N_NODES * MASK_ULL] = m1;
      maskU[o + 2 * (size_t)N_NODES * MASK_ULL] = m2;
    }
  }
}

// ---------------------------------------------------------------- pack g[j][f] -> gP[j/8][f][8]  (coalesced MFMA B-frags)
template<int C>
__global__ __launch_bounds__(256) void pack_kernel(const bf16* __restrict__ src,
                                                   bf16* __restrict__ dst) {
  __shared__ bf16 t[64][72];
  int j0 = blockIdx.x * 64, f0 = blockIdx.y * 64;
  int rr = threadIdx.x >> 4;
  int cc = (threadIdx.x & 15) * 4;
#pragma unroll
  for (int p = 0; p < 4; ++p) {
    int r = p * 16 + rr;
    *(bf16x4*)&t[r][cc] = *(const bf16x4*)&src[(size_t)(j0 + r) * C + f0 + cc];
  }
  __syncthreads();
  int f = threadIdx.x & 63, g = threadIdx.x >> 6;
#pragma unroll
  for (int q = 0; q < 2; ++q) {
    int p = g * 2 + q;
    bf16x8 v = { t[p*8+0][f], t[p*8+1][f], t[p*8+2][f], t[p*8+3][f],
                 t[p*8+4][f], t[p*8+5][f], t[p*8+6][f], t[p*8+7][f] };
    *(bf16x8*)&dst[ ((size_t)((j0 >> 3) + p) * C + f0 + f) * 8 ] = v;
  }
}

// ---------------------------------------------------------------- head projections -> exp-factor arrays
// elp=e^sl, eln=e^{0.2 sl}, erp=e^sr, ern=e^{0.2 sr}  (via exp2 with log2e prescale)
// 16 lanes per row, shfl-reduce; 16 rows per 256-thread block.
template<int NCPB, int NH>
__global__ __launch_bounds__(256) void head_proj_kernel(
    const bf16* __restrict__ g, int ldg,
    const float* __restrict__ a0, const float* __restrict__ a1, const float* __restrict__ a2,
    float* __restrict__ elp, float* __restrict__ eln,
    float* __restrict__ erp, float* __restrict__ ern) {
  int c = blockIdx.y;
  int i = blockIdx.x * 16 + (threadIdx.x >> 4);
  int b = c / NCPB;
  const float* a = (b == 0) ? a0 : (b == 1) ? a1 : a2;
  int f0 = (threadIdx.x & 15) * (NH / 16);
  const bf16* gr = g + (size_t)i * ldg + c * NH + f0;
  float accl = 0.f, accr = 0.f;
#pragma unroll
  for (int k = 0; k < NH / 16; k += 4) {
    bf16x4 v = *(const bf16x4*)&gr[k];
#pragma unroll
    for (int e = 0; e < 4; ++e) {
      float gv = (float)v[e];
      accl += gv * a[f0 + k + e];
      accr += gv * a[NH + f0 + k + e];
    }
  }
#pragma unroll
  for (int m = 1; m < 16; m <<= 1) {
    accl += __shfl_xor(accl, m, 64);
    accr += __shfl_xor(accr, m, 64);
  }
  if ((threadIdx.x & 15) == 0) {
    int o = c * N_NODES + i;
    elp[o] = fexp2(accl * LOG2E);
    eln[o] = fexp2(0.2f * accl * LOG2E);
    erp[o] = fexp2(accr * LOG2E);
    ern[o] = fexp2(0.2f * accr * LOG2E);
  }
}

// ---------------------------------------------------------------- column means (uniform-softmax fallback)
__global__ __launch_bounds__(256) void colmean_kernel(const bf16* __restrict__ g, int C,
                                                      float* __restrict__ out) {
  int c = blockIdx.x * 256 + threadIdx.x;
  if (c >= C) return;
  int r0 = blockIdx.y * 128;
  float s = 0.f;
  for (int r = r0; r < r0 + 128; ++r) s += (float)g[(size_t)r * C + c];
  atomAddF(&out[c], s * (1.0f / N_NODES));
}

// ---------------------------------------------------------------- GEMM 64x64 tile: C = A * B^T (+bias, leaky, +res)
template<bool BIAS, bool LEAKY, bool RES, bool F32OUT>
__global__ __launch_bounds__(256) void gemm64_kernel(
    const bf16* __restrict__ A, int lda, int aZoff,
    const bf16* __restrict__ B0, const bf16* __restrict__ B1, const bf16* __restrict__ B2,
    int ldb, void* __restrict__ Cout, int ldc, int cZoff, int K,
    const float* __restrict__ bias, const float* __restrict__ res) {
  __shared__ bf16 As[64 * 64];
  __shared__ bf16 Bs[64 * 64];
  int z = blockIdx.z;
  const bf16* Ab = A + (size_t)z * aZoff;
  const bf16* Bb = (z == 0) ? B0 : (z == 1) ? B1 : B2;
  int m0 = blockIdx.x * 64, n0 = blockIdx.y * 64;
  int tid = threadIdx.x;
  int lane = tid & 63, wave = tid >> 6;
  int wm = wave >> 1, wn = wave & 1;
  int l15 = lane & 15, lk = lane >> 4;
  f32x4 acc[2][2] = {};
  for (int kt = 0; kt < K; kt += 64) {
#pragma unroll
    for (int h = 0; h < 2; ++h) {
      int u = h * 256 + tid;
      int r = u >> 3, up = u & 7;
      int ul = up ^ (r & 7);
      *(bf16x8*)&As[r * 64 + up * 8] = *(const bf16x8*)&Ab[(size_t)(m0 + r) * lda + kt + ul * 8];
      *(bf16x8*)&Bs[r * 64 + up * 8] = *(const bf16x8*)&Bb[(size_t)(n0 + r) * ldb + kt + ul * 8];
    }
    __syncthreads();
#pragma unroll
    for (int s = 0; s < 2; ++s) {
      bf16x8 af[2], bfr[2];
      int u = s * 4 + lk;
#pragma unroll
      for (int mi = 0; mi < 2; ++mi) {
        int r = wm * 32 + mi * 16 + l15;
        af[mi] = *(const bf16x8*)&As[r * 64 + (u ^ (r & 7)) * 8];
      }
#pragma unroll
      for (int ni = 0; ni < 2; ++ni) {
        int r = wn * 32 + ni * 16 + l15;
        bfr[ni] = *(const bf16x8*)&Bs[r * 64 + (u ^ (r & 7)) * 8];
      }
#pragma unroll
      for (int mi = 0; mi < 2; ++mi)
#pragma unroll
        for (int ni = 0; ni < 2; ++ni)
          acc[mi][ni] = __builtin_amdgcn_mfma_f32_16x16x32_bf16(af[mi], bfr[ni], acc[mi][ni], 0, 0, 0);
    }
    __syncthreads();
  }
#pragma unroll
  for (int mi = 0; mi < 2; ++mi)
#pragma unroll
    for (int ni = 0; ni < 2; ++ni)
#pragma unroll
      for (int r = 0; r < 4; ++r) {
        int i = m0 + wm * 32 + mi * 16 + lk * 4 + r;
        int col = z * cZoff + n0 + wn * 32 + ni * 16 + l15;
        float v = acc[mi][ni][r];
        if (BIAS) v += bias[col];
        if (LEAKY) v = (v >= 0.f) ? v : 0.01f * v;
        if (RES) v += res[(size_t)i * ldc + col];
        if (F32OUT) ((float*)Cout)[(size_t)i * ldc + col] = v;
        else        ((bf16*)Cout)[(size_t)i * ldc + col] = (bf16)v;
      }
}

// ---------------------------------------------------------------- unified attention partial kernel
// block = 64 rows x (combo) x (chunk q). Wave w owns rows [i0+16w, i0+16w+16) and
// traverses the full chunk (4 waves share the gP stream). P built from precomputed
// exp factors: p = (elp*erp >= 1) ? elp*erp : eln*ern  (== exp(leaky(sl+sr))).
// Denominator = 5th MFMA with B = ones. No LDS/barriers/atomics.
template<bool L1>
__global__ __launch_bounds__(256) void att_kernel(
    const bf16* __restrict__ gP,
    const float* __restrict__ elpA, const float* __restrict__ elnA,
    const float* __restrict__ erpA, const float* __restrict__ ernA,
    const unsigned char* __restrict__ maskB,
    const int* __restrict__ dnum, const int* __restrict__ snum,
    float* __restrict__ accP, float* __restrict__ lP) {
  constexpr int C = L1 ? C1 : C2;
  constexpr int NSENT = L1 ? 6 : 4;   // # combos belonging to the sent branch
  int c = blockIdx.y;
  int b = L1 ? (c / 6) : (c >> 2);
  int colbase = L1 ? c * 64 : (b * 256 + (c & 3) * 64);
  int sidx = L1 ? c : b;
  int q = blockIdx.z;
  int Qb = (b == 0) ? QS : 1;
  if (q >= Qb) return;
  int dn = dnum[0], sn = snum[0];
  int bb1 = N_NODES - sn - dn, bb2 = N_NODES - dn;
  int jlo = (b == 0) ? 0 : (b == 1) ? bb1 : bb2;
  int jhi = (b == 0) ? bb1 : (b == 1) ? bb2 : N_NODES;
  int len = jhi - jlo;
  int wlo = bnd32(jlo, jhi, len, q, Qb);
  int whi = bnd32(jlo, jhi, len, q + 1, Qb);
  if (wlo >= whi) return;   // fin skips empty slices with the same test

  int wave = threadIdx.x >> 6, lane = threadIdx.x & 63;
  int l15 = lane & 15, lk = lane >> 4;
  int row0 = blockIdx.x * 64 + wave * 16;
  int ip = row0 + l15;
  float elp = elpA[sidx * N_NODES + ip];
  float eln = elnA[sidx * N_NODES + ip];
  const float* erpB = erpA + sidx * N_NODES;
  const float* ernB = ernA + sidx * N_NODES;
  const unsigned char* mrow = maskB + (size_t)b * MASK_BSTRIDE + (size_t)ip * MASK_BYTES;
  bf16x8 ones;
#pragma unroll
  for (int e = 0; e < 8; ++e) ones[e] = (bf16)1.0f;
  f32x4 acc[4] = {};
  f32x4 accl = {};
  for (int jt = wlo; jt < whi; jt += 32) {
    int jb = jt + lk * 8;
    unsigned int mb = mrow[jb >> 3];
    float4 p0 = *(const float4*)&erpB[jb];
    float4 p1 = *(const float4*)&erpB[jb + 4];
    float4 n0 = *(const float4*)&ernB[jb];
    float4 n1 = *(const float4*)&ernB[jb + 4];
    float pv[8] = { p0.x, p0.y, p0.z, p0.w, p1.x, p1.y, p1.z, p1.w };
    float nv[8] = { n0.x, n0.y, n0.z, n0.w, n1.x, n1.y, n1.z, n1.w };
    bf16x8 a8;
#pragma unroll
    for (int e = 0; e < 8; ++e) {
      float z = elp * pv[e];
      float w = eln * nv[e];
      float p = (z >= 1.f) ? z : w;
      p = ((mb >> e) & 1u) ? p : 0.f;
      a8[e] = (bf16)p;
    }
    size_t pbase = (size_t)(jb >> 3) * C * 8;
#pragma unroll
    for (int nf = 0; nf < 4; ++nf) {
      bf16x8 b8 = *(const bf16x8*)&gP[pbase + (size_t)(colbase + nf * 16 + l15) * 8];
      acc[nf] = __builtin_amdgcn_mfma_f32_16x16x32_bf16(a8, b8, acc[nf], 0, 0, 0);
    }
    accl = __builtin_amdgcn_mfma_f32_16x16x32_bf16(a8, ones, accl, 0, 0, 0);
  }
  int slot = (b == 0) ? (c * QS + q) : (NSENT * QS + (c - NSENT));
  float* ap = accP + ((size_t)slot * N_NODES + row0) * 64;
#pragma unroll
  for (int nf = 0; nf < 4; ++nf)
#pragma unroll
    for (int r = 0; r < 4; ++r)
      ap[(lk * 4 + r) * 64 + nf * 16 + l15] = acc[nf][r];
  if (l15 == 0) {
#pragma unroll
    for (int r = 0; r < 4; ++r)
      lP[(size_t)slot * N_NODES + row0 + lk * 4 + r] = accl[r];
  }
}

// ---------------------------------------------------------------- finalize layer 1: sum slices, /l (or gmean), ELU
__global__ __launch_bounds__(256) void fin1_kernel(
    const float* __restrict__ accP, const float* __restrict__ lP,
    const float* __restrict__ gm, const int* __restrict__ dnum, const int* __restrict__ snum,
    bf16* __restrict__ out1) {
  int t = blockIdx.x * 256 + threadIdx.x;
  int i = t / (C1 / 8), f0 = (t - i * (C1 / 8)) * 8;
  int c = f0 >> 6;
  int b = c / 6;
  int dn = dnum[0], sn = snum[0];
  int bb1 = N_NODES - sn - dn, bb2 = N_NODES - dn;
  int jlo = (b == 0) ? 0 : (b == 1) ? bb1 : bb2;
  int jhi = (b == 0) ? bb1 : (b == 1) ? bb2 : N_NODES;
  int len = jhi - jlo;
  int Qb = (b == 0) ? QS : 1;
  float l = 0.f;
  float a[8] = {0.f,0.f,0.f,0.f,0.f,0.f,0.f,0.f};
  if (len > 0) {
    for (int q = 0; q < Qb; ++q) {
      if (bnd32(jlo, jhi, len, q, Qb) >= bnd32(jlo, jhi, len, q + 1, Qb)) continue;
      int slot = (b == 0) ? (c * QS + q) : (6 * QS + (c - 6));
      l += lP[(size_t)slot * N_NODES + i];
      const float* ap = &accP[((size_t)slot * N_NODES + i) * 64 + (f0 & 63)];
      f32x4 v0 = *(const f32x4*)ap, v1 = *(const f32x4*)(ap + 4);
#pragma unroll
      for (int e = 0; e < 4; ++e) { a[e] += v0[e]; a[e + 4] += v1[e]; }
    }
  }
  float inv = (l > 0.f) ? 1.f / l : 0.f;
  bf16x8 o;
#pragma unroll
  for (int e = 0; e < 8; ++e) {
    float v = (l > 0.f) ? a[e] * inv : gm[f0 + e];
    v = (v > 0.f) ? v : (__expf(v) - 1.f);   // ELU
    o[e] = (bf16)v;
  }
  *(bf16x8*)&out1[(size_t)i * C1 + f0] = o;
}

// ---------------------------------------------------------------- finalize layer 2: sum slices, /l (or gmean), +residual -> fused
__global__ __launch_bounds__(256) void fin2_kernel(
    const float* __restrict__ accP, const float* __restrict__ lP,
    const float* __restrict__ gm, const float* __restrict__ feat,
    const int* __restrict__ dnum, const int* __restrict__ snum,
    bf16* __restrict__ fused) {
  int t = blockIdx.x * 256 + threadIdx.x;
  int i = t / (C2 / 8), f0 = (t - i * (C2 / 8)) * 8;
  int b = f0 >> 8;
  int fi = f0 & 255;
  int fc = (f0 >> 6) & 3;
  int c = b * 4 + fc;
  int dn = dnum[0], sn = snum[0];
  int bb1 = N_NODES - sn - dn, bb2 = N_NODES - dn;
  int jlo = (b == 0) ? 0 : (b == 1) ? bb1 : bb2;
  int jhi = (b == 0) ? bb1 : (b == 1) ? bb2 : N_NODES;
  int len = jhi - jlo;
  int Qb = (b == 0) ? QS : 1;
  float l = 0.f;
  float a[8] = {0.f,0.f,0.f,0.f,0.f,0.f,0.f,0.f};
  if (len > 0) {
    for (int q = 0; q < Qb; ++q) {
      if (bnd32(jlo, jhi, len, q, Qb) >= bnd32(jlo, jhi, len, q + 1, Qb)) continue;
      int slot = (b == 0) ? (c * QS + q) : (4 * QS + (c - 4));
      l += lP[(size_t)slot * N_NODES + i];
      const float* ap = &accP[((size_t)slot * N_NODES + i) * 64 + (f0 & 63)];
      f32x4 v0 = *(const f32x4*)ap, v1 = *(const f32x4*)(ap + 4);
#pragma unroll
      for (int e = 0; e < 4; ++e) { a[e] += v0[e]; a[e + 4] += v1[e]; }
    }
  }
  float inv = (l > 0.f) ? 1.f / l : 0.f;
  bf16x8 o;
#pragma unroll
  for (int e = 0; e < 8; ++e) {
    float v = (l > 0.f) ? a[e] * inv : gm[f0 + e];
    v += feat[(size_t)i * D_IN + fi + e];
    o[e] = (bf16)v;
  }
  *(bf16x8*)&fused[(size_t)i * C2 + (2 - b) * D_IN + fi] = o;
}

// ---------------------------------------------------------------- launch
extern "C" void kernel_launch(void* const* d_in, const int* in_sizes, int n_in,
                              void* d_out, int out_size, void* d_ws, size_t ws_size,
                              hipStream_t stream) {
  (void)in_sizes; (void)n_in; (void)out_size; (void)ws_size;
  const float* feature = (const float*)d_in[0];
  const int*   adj     = (const int*)d_in[1];
  const int*   dnum    = (const int*)d_in[2];
  const int*   snum    = (const int*)d_in[3];
  const float* W1s = (const float*)d_in[4];  const float* a1s = (const float*)d_in[5];
  const float* W2s = (const float*)d_in[6];  const float* a2s = (const float*)d_in[7];
  const float* W1e = (const float*)d_in[8];  const float* a1e = (const float*)d_in[9];
  const float* W2e = (const float*)d_in[10]; const float* a2e = (const float*)d_in[11];
  const float* W1d = (const float*)d_in[12]; const float* a1d = (const float*)d_in[13];
  const float* W2d = (const float*)d_in[14]; const float* a2d = (const float*)d_in[15];
  const float* fW  = (const float*)d_in[16]; const float* fB  = (const float*)d_in[17];
  const float* w0  = (const float*)d_in[18]; const float* b0  = (const float*)d_in[19];
  const float* w1  = (const float*)d_in[20]; const float* b1  = (const float*)d_in[21];
  const float* w2  = (const float*)d_in[22]; const float* b2  = (const float*)d_in[23];

  char* ws = (char*)d_ws;
  size_t off = 0;
  auto alloc = [&](size_t bytes) { void* p = ws + off; off += (bytes + 255) & ~(size_t)255; return p; };

  unsigned long long* maskU = (unsigned long long*)alloc(3 * (size_t)N_NODES * MASK_ULL * 8);
  bf16* fbf   = (bf16*)alloc((size_t)N_NODES * D_IN * 2);
  bf16* w1b0  = (bf16*)alloc(HIDDEN * D_IN * 2);
  bf16* w1b1  = (bf16*)alloc(HIDDEN * D_IN * 2);
  bf16* w1b2  = (bf16*)alloc(HIDDEN * D_IN * 2);
  bf16* w2b0  = (bf16*)alloc(D_IN * HIDDEN * 2);
  bf16* w2b1  = (bf16*)alloc(D_IN * HIDDEN * 2);
  bf16* w2b2  = (bf16*)alloc(D_IN * HIDDEN * 2);
  bf16* wfusb = (bf16*)alloc(D_IN * C2 * 2);
  bf16* wf0b  = (bf16*)alloc(HIDDEN * D_IN * 2);
  bf16* wf1b  = (bf16*)alloc(HIDDEN * HIDDEN * 2);
  bf16* wf2b  = (bf16*)alloc(D_IN * HIDDEN * 2);
  bf16* g1    = (bf16*)alloc((size_t)N_NODES * C1 * 2);
  bf16* gP1   = (bf16*)alloc((size_t)N_NODES * C1 * 2);
  bf16* out1  = (bf16*)alloc((size_t)N_NODES * C1 * 2);
  bf16* g2    = (bf16*)alloc((size_t)N_NODES * C2 * 2);
  bf16* gP2   = (bf16*)alloc((size_t)N_NODES * C2 * 2);
  bf16* fusedB= (bf16*)alloc((size_t)N_NODES * C2 * 2);
  bf16* h0    = (bf16*)alloc((size_t)N_NODES * D_IN * 2);
  bf16* h1    = (bf16*)alloc((size_t)N_NODES * HIDDEN * 2);
  bf16* h2    = (bf16*)alloc((size_t)N_NODES * HIDDEN * 2);
  // exp-factor arrays (layer1: 18 combos, layer2: 3)
  float* elp1 = (float*)alloc(18 * N_NODES * 4);
  float* eln1 = (float*)alloc(18 * N_NODES * 4);
  float* erp1 = (float*)alloc(18 * N_NODES * 4);
  float* ern1 = (float*)alloc(18 * N_NODES * 4);
  float* elp2 = (float*)alloc(3 * N_NODES * 4);
  float* eln2 = (float*)alloc(3 * N_NODES * 4);
  float* erp2 = (float*)alloc(3 * N_NODES * 4);
  float* ern2 = (float*)alloc(3 * N_NODES * 4);
  // partial buffers: att1 uses 36 slots (6 sent x4 + 12), att2 uses 24 (4x4 + 8) -> union 36
  float* accU = (float*)alloc((size_t)36 * N_NODES * 64 * 4);  // 28.3 MB
  float* lU   = (float*)alloc((size_t)36 * N_NODES * 4);
  // zero-initialized region: colmeans only
  size_t zoff = off;
  float* gm1  = (float*)alloc(C1 * 4);
  float* gm2  = (float*)alloc(C2 * 4);
  size_t zbytes = off - zoff;
  const unsigned char* maskBytes = (const unsigned char*)maskU;

  hipMemsetAsync(ws + zoff, 0, zbytes, stream);

  // 1) casts
  CastArgs ca;
  {
    const float* srcs[11] = { feature, W1s, W1e, W1d, W2s, W2e, W2d, fW, w0, w1, w2 };
    bf16* dsts[11] = { fbf, w1b0, w1b1, w1b2, w2b0, w2b1, w2b2, wfusb, wf0b, wf1b, wf2b };
    int counts[11] = { N_NODES*D_IN, HIDDEN*D_IN, HIDDEN*D_IN, HIDDEN*D_IN,
                       D_IN*HIDDEN, D_IN*HIDDEN, D_IN*HIDDEN, D_IN*C2,
                       HIDDEN*D_IN, HIDDEN*HIDDEN, D_IN*HIDDEN };
    int cum = 0;
    for (int k = 0; k < 11; ++k) { ca.src[k] = srcs[k]; ca.dst[k] = dsts[k]; ca.cum4[k] = cum; cum += counts[k] / 4; }
    ca.cum4[11] = cum;
    cast_all_kernel<<<cum / 256, 256, 0, stream>>>(ca);
  }
  // 2) pack adjacency bits (3 per-branch masks, range folded in)
  pack_adj_kernel<<<N_NODES, 256, 0, stream>>>(adj, maskU, dnum, snum);
  // 3) g1 = f @ W1^T (3 branches via z)
  gemm64_kernel<false,false,false,false><<<dim3(48,6,3), 256, 0, stream>>>(
      fbf, D_IN, 0, w1b0, w1b1, w1b2, D_IN, g1, C1, HIDDEN, D_IN, nullptr, nullptr);
  // 4) pack g1 -> gP1
  pack_kernel<C1><<<dim3(48,18), 256, 0, stream>>>(g1, gP1);
  // 5) exp factors layer1
  head_proj_kernel<HEADS, NH1><<<dim3(192,18), 256, 0, stream>>>(g1, C1, a1s, a1e, a1d, elp1, eln1, erp1, ern1);
  // 6) colmean g1
  colmean_kernel<<<dim3((C1 + 255) / 256, 24), 256, 0, stream>>>(g1, C1, gm1);
  // 7) attention 1 partials
  att_kernel<true><<<dim3(48, 18, QS), 256, 0, stream>>>(gP1, elp1, eln1, erp1, ern1, maskBytes, dnum, snum, accU, lU);
  // 7b) finalize 1 (+ELU)
  fin1_kernel<<<N_NODES * (C1 / 8) / 256, 256, 0, stream>>>(accU, lU, gm1, dnum, snum, out1);
  // 8) g2 = out1 @ W2^T per branch
  gemm64_kernel<false,false,false,false><<<dim3(48,4,3), 256, 0, stream>>>(
      out1, C1, HIDDEN, w2b0, w2b1, w2b2, HIDDEN, g2, C2, D_IN, HIDDEN, nullptr, nullptr);
  // 9) pack g2 -> gP2
  pack_kernel<C2><<<dim3(48,12), 256, 0, stream>>>(g2, gP2);
  // 10) exp factors layer2
  head_proj_kernel<1, D_IN><<<dim3(192,3), 256, 0, stream>>>(g2, C2, a2s, a2e, a2d, elp2, eln2, erp2, ern2);
  // 11) colmean g2
  colmean_kernel<<<dim3((C2 + 255) / 256, 24), 256, 0, stream>>>(g2, C2, gm2);
  // 12) attention 2 partials (combos = branch x 4 f-chunks)
  att_kernel<false><<<dim3(48, 12, QS), 256, 0, stream>>>(gP2, elp2, eln2, erp2, ern2, maskBytes, dnum, snum, accU, lU);
  // 12b) finalize 2 (+residual, writes fused [doc,sect,sent])
  fin2_kernel<<<N_NODES * (C2 / 8) / 256, 256, 0, stream>>>(accU, lU, gm2, feature, dnum, snum, fusedB);
  // 13) fusion: h0 = leaky(fused @ fW^T + fB)
  gemm64_kernel<true,true,false,false><<<dim3(48,4,1), 256, 0, stream>>>(
      fusedB, C2, 0, wfusb, wfusb, wfusb, C2, h0, D_IN, 0, C2, fB, nullptr);
  // 14) ffn0: h1 = leaky(h0 @ w0^T + b0)
  gemm64_kernel<true,true,false,false><<<dim3(48,6,1), 256, 0, stream>>>(
      h0, D_IN, 0, wf0b, wf0b, wf0b, D_IN, h1, HIDDEN, 0, D_IN, b0, nullptr);
  // 15) ffn1: h2 = leaky(h1 @ w1^T + b1)
  gemm64_kernel<true,true,false,false><<<dim3(48,6,1), 256, 0, stream>>>(
      h1, HIDDEN, 0, wf1b, wf1b, wf1b, HIDDEN, h2, HIDDEN, 0, HIDDEN, b1, nullptr);
  // 16) ffn2: out = leaky(h2 @ w2^T + b2) + f   (fp32 out)
  gemm64_kernel<true,true,true,true><<<dim3(48,4,1), 256, 0, stream>>>(
      h2, HIDDEN, 0, wf2b, wf2b, wf2b, HIDDEN, d_out, D_IN, 0, HIDDEN, b2, feature);
}

// Round 6
// 285.472 us; speedup vs baseline: 1.1244x; 1.1244x over previous
//
#include <hip/hip_runtime.h>
#include <stdint.h>

#define N_NODES 3072
#define D_IN    256
#define HIDDEN  384
#define HEADS   6
#define NH1     64
#define C1      1152   // 3*HIDDEN
#define C2      768    // 3*D_IN
#define MASK_ULL   48  // 3072/64 per row
#define MASK_BYTES 384 // 3072/8 per row
#define MASK_BSTRIDE ((size_t)N_NODES * MASK_BYTES)  // per-branch mask stride (bytes)
#define QS      6      // j-splits for the sent branch (sect/doc get 1)
#define LOG2E   1.4426950408889634f

typedef __bf16 bf16;
typedef __bf16 bf16x8 __attribute__((ext_vector_type(8)));
typedef __bf16 bf16x4 __attribute__((ext_vector_type(4)));
typedef float  f32x4  __attribute__((ext_vector_type(4)));

__device__ __forceinline__ void atomAddF(float* p, float v) {
  __hip_atomic_fetch_add(p, v, __ATOMIC_RELAXED, __HIP_MEMORY_SCOPE_AGENT);
}
__device__ __forceinline__ float fexp2(float x) {   // D = 2^S0
  float r; asm("v_exp_f32 %0, %1" : "=v"(r) : "v"(x)); return r;
}
// 32-aligned chunk boundary: q in [0,Qb]; B(0) floors jlo, B(Qb) ceils jhi.
__device__ __forceinline__ int bnd32(int jlo, int jhi, int len, int q, int Qb) {
  return (q >= Qb) ? ((jhi + 31) & ~31) : ((jlo + (len * q) / Qb) & ~31);
}

// ---------------------------------------------------------------- cast fp32->bf16
struct CastArgs {
  const float* src[11];
  bf16*        dst[11];
  int          cum4[12];
};

__global__ __launch_bounds__(256) void cast_all_kernel(CastArgs A) {
  int g = blockIdx.x * 256 + threadIdx.x;
  int j = 0;
#pragma unroll
  for (int k = 1; k < 11; ++k) j += (g >= A.cum4[k]);
  int e = (g - A.cum4[j]) * 4;
  float4 v = *(const float4*)(A.src[j] + e);
  bf16x4 o = { (bf16)v.x, (bf16)v.y, (bf16)v.z, (bf16)v.w };
  *(bf16x4*)(A.dst[j] + e) = o;
}

// ---------------------------------------------------------------- adj -> 3 per-branch bitmasks (range folded in)
__global__ __launch_bounds__(256) void pack_adj_kernel(const int* __restrict__ adj,
                                                       unsigned long long* __restrict__ maskU,
                                                       const int* __restrict__ dnum,
                                                       const int* __restrict__ snum) {
  int dn = dnum[0], sn = snum[0];
  int bb1 = N_NODES - sn - dn, bb2 = N_NODES - dn;
  int row = blockIdx.x;
  const int* ar = adj + (size_t)row * N_NODES;
  int lane = threadIdx.x & 63, wave = threadIdx.x >> 6;
#pragma unroll
  for (int it = 0; it < N_NODES / 256; ++it) {
    int j = it * 256 + wave * 64 + lane;
    bool a = ar[j] != 0;
    unsigned long long m0 = __ballot(a && (j < bb1));
    unsigned long long m1 = __ballot(a && (j >= bb1) && (j < bb2));
    unsigned long long m2 = __ballot(a && (j >= bb2));
    if (lane == 0) {
      size_t o = (size_t)row * MASK_ULL + it * 4 + wave;
      maskU[o] = m0;
      maskU[o + (size_t)N_NODES * MASK_ULL] = m1;
      maskU[o + 2 * (size_t)N_NODES * MASK_ULL] = m2;
    }
  }
}

// ---------------------------------------------------------------- pack g[j][f] -> gP[j/8][f][8] + column means (fused)
template<int C>
__global__ __launch_bounds__(256) void pack_kernel(const bf16* __restrict__ src,
                                                   bf16* __restrict__ dst,
                                                   float* __restrict__ gm) {
  __shared__ bf16 t[64][72];
  int j0 = blockIdx.x * 64, f0 = blockIdx.y * 64;
  int rr = threadIdx.x >> 4;
  int cc = (threadIdx.x & 15) * 4;
#pragma unroll
  for (int p = 0; p < 4; ++p) {
    int r = p * 16 + rr;
    *(bf16x4*)&t[r][cc] = *(const bf16x4*)&src[(size_t)(j0 + r) * C + f0 + cc];
  }
  __syncthreads();
  int f = threadIdx.x & 63, g = threadIdx.x >> 6;
#pragma unroll
  for (int q = 0; q < 2; ++q) {
    int p = g * 2 + q;
    bf16x8 v = { t[p*8+0][f], t[p*8+1][f], t[p*8+2][f], t[p*8+3][f],
                 t[p*8+4][f], t[p*8+5][f], t[p*8+6][f], t[p*8+7][f] };
    *(bf16x8*)&dst[ ((size_t)((j0 >> 3) + p) * C + f0 + f) * 8 ] = v;
  }
  // fused column-mean partial (tile already staged)
  float s = 0.f;
#pragma unroll
  for (int k = 0; k < 16; ++k) s += (float)t[g * 16 + k][f];
  atomAddF(&gm[f0 + f], s * (1.0f / N_NODES));
}

// ---------------------------------------------------------------- head projections -> exp-factor arrays
template<int NCPB, int NH>
__global__ __launch_bounds__(256) void head_proj_kernel(
    const bf16* __restrict__ g, int ldg,
    const float* __restrict__ a0, const float* __restrict__ a1, const float* __restrict__ a2,
    float* __restrict__ elp, float* __restrict__ eln,
    float* __restrict__ erp, float* __restrict__ ern) {
  int c = blockIdx.y;
  int i = blockIdx.x * 16 + (threadIdx.x >> 4);
  int b = c / NCPB;
  const float* a = (b == 0) ? a0 : (b == 1) ? a1 : a2;
  int f0 = (threadIdx.x & 15) * (NH / 16);
  const bf16* gr = g + (size_t)i * ldg + c * NH + f0;
  float accl = 0.f, accr = 0.f;
#pragma unroll
  for (int k = 0; k < NH / 16; k += 4) {
    bf16x4 v = *(const bf16x4*)&gr[k];
#pragma unroll
    for (int e = 0; e < 4; ++e) {
      float gv = (float)v[e];
      accl += gv * a[f0 + k + e];
      accr += gv * a[NH + f0 + k + e];
    }
  }
#pragma unroll
  for (int m = 1; m < 16; m <<= 1) {
    accl += __shfl_xor(accl, m, 64);
    accr += __shfl_xor(accr, m, 64);
  }
  if ((threadIdx.x & 15) == 0) {
    int o = c * N_NODES + i;
    elp[o] = fexp2(accl * LOG2E);
    eln[o] = fexp2(0.2f * accl * LOG2E);
    erp[o] = fexp2(accr * LOG2E);
    ern[o] = fexp2(0.2f * accr * LOG2E);
  }
}

// ---------------------------------------------------------------- GEMM 64x64 tile: C = A * B^T (+bias, leaky, +res)
template<bool BIAS, bool LEAKY, bool RES, bool F32OUT>
__global__ __launch_bounds__(256) void gemm64_kernel(
    const bf16* __restrict__ A, int lda, int aZoff,
    const bf16* __restrict__ B0, const bf16* __restrict__ B1, const bf16* __restrict__ B2,
    int ldb, void* __restrict__ Cout, int ldc, int cZoff, int K,
    const float* __restrict__ bias, const float* __restrict__ res) {
  __shared__ bf16 As[64 * 64];
  __shared__ bf16 Bs[64 * 64];
  int z = blockIdx.z;
  const bf16* Ab = A + (size_t)z * aZoff;
  const bf16* Bb = (z == 0) ? B0 : (z == 1) ? B1 : B2;
  int m0 = blockIdx.x * 64, n0 = blockIdx.y * 64;
  int tid = threadIdx.x;
  int lane = tid & 63, wave = tid >> 6;
  int wm = wave >> 1, wn = wave & 1;
  int l15 = lane & 15, lk = lane >> 4;
  f32x4 acc[2][2] = {};
  for (int kt = 0; kt < K; kt += 64) {
#pragma unroll
    for (int h = 0; h < 2; ++h) {
      int u = h * 256 + tid;
      int r = u >> 3, up = u & 7;
      int ul = up ^ (r & 7);
      *(bf16x8*)&As[r * 64 + up * 8] = *(const bf16x8*)&Ab[(size_t)(m0 + r) * lda + kt + ul * 8];
      *(bf16x8*)&Bs[r * 64 + up * 8] = *(const bf16x8*)&Bb[(size_t)(n0 + r) * ldb + kt + ul * 8];
    }
    __syncthreads();
#pragma unroll
    for (int s = 0; s < 2; ++s) {
      bf16x8 af[2], bfr[2];
      int u = s * 4 + lk;
#pragma unroll
      for (int mi = 0; mi < 2; ++mi) {
        int r = wm * 32 + mi * 16 + l15;
        af[mi] = *(const bf16x8*)&As[r * 64 + (u ^ (r & 7)) * 8];
      }
#pragma unroll
      for (int ni = 0; ni < 2; ++ni) {
        int r = wn * 32 + ni * 16 + l15;
        bfr[ni] = *(const bf16x8*)&Bs[r * 64 + (u ^ (r & 7)) * 8];
      }
#pragma unroll
      for (int mi = 0; mi < 2; ++mi)
#pragma unroll
        for (int ni = 0; ni < 2; ++ni)
          acc[mi][ni] = __builtin_amdgcn_mfma_f32_16x16x32_bf16(af[mi], bfr[ni], acc[mi][ni], 0, 0, 0);
    }
    __syncthreads();
  }
#pragma unroll
  for (int mi = 0; mi < 2; ++mi)
#pragma unroll
    for (int ni = 0; ni < 2; ++ni)
#pragma unroll
      for (int r = 0; r < 4; ++r) {
        int i = m0 + wm * 32 + mi * 16 + lk * 4 + r;
        int col = z * cZoff + n0 + wn * 32 + ni * 16 + l15;
        float v = acc[mi][ni][r];
        if (BIAS) v += bias[col];
        if (LEAKY) v = (v >= 0.f) ? v : 0.01f * v;
        if (RES) v += res[(size_t)i * ldc + col];
        if (F32OUT) ((float*)Cout)[(size_t)i * ldc + col] = v;
        else        ((bf16*)Cout)[(size_t)i * ldc + col] = (bf16)v;
      }
}

// ---------------------------------------------------------------- attention: 64 rows x 64 cols per WAVE
// All loaded bytes (erp/ern/mask/gP-fragments) feed 4 row-groups -> 4x arithmetic
// intensity vs 16-row waves. Explicit 2-stage prefetch hides L2 latency.
struct Stream {
  float4 p0, p1, n0, n1;
  unsigned int m0, m1, m2, m3;
  bf16x8 b0, b1, b2, b3;
};

template<int C>
__device__ __forceinline__ void load_stream(
    Stream& s, int jb,
    const float* __restrict__ erpB, const float* __restrict__ ernB,
    const unsigned char* mr0, const unsigned char* mr1,
    const unsigned char* mr2, const unsigned char* mr3,
    const bf16* __restrict__ gPl) {
  s.p0 = *(const float4*)&erpB[jb];
  s.p1 = *(const float4*)&erpB[jb + 4];
  s.n0 = *(const float4*)&ernB[jb];
  s.n1 = *(const float4*)&ernB[jb + 4];
  int mo = jb >> 3;
  s.m0 = mr0[mo]; s.m1 = mr1[mo]; s.m2 = mr2[mo]; s.m3 = mr3[mo];
  const bf16* gp = gPl + (size_t)mo * C * 8;
  s.b0 = *(const bf16x8*)(gp + 0);
  s.b1 = *(const bf16x8*)(gp + 128);
  s.b2 = *(const bf16x8*)(gp + 256);
  s.b3 = *(const bf16x8*)(gp + 384);
}

template<bool L1>
__global__ __launch_bounds__(256) void att_kernel(
    const bf16* __restrict__ gP,
    const float* __restrict__ elpA, const float* __restrict__ elnA,
    const float* __restrict__ erpA, const float* __restrict__ ernA,
    const unsigned char* __restrict__ maskB,
    const int* __restrict__ dnum, const int* __restrict__ snum,
    float* __restrict__ accP, float* __restrict__ lP) {
  constexpr int C = L1 ? C1 : C2;
  int c = blockIdx.y;
  int b = L1 ? (c / 6) : (c >> 2);
  int colbase = L1 ? c * 64 : (b * 256 + (c & 3) * 64);
  int sidx = L1 ? c : b;
  int q = blockIdx.z;
  int Qb = (b == 0) ? QS : 1;
  if (q >= Qb) return;
  int dn = dnum[0], sn = snum[0];
  int bb1 = N_NODES - sn - dn, bb2 = N_NODES - dn;
  int jlo = (b == 0) ? 0 : (b == 1) ? bb1 : bb2;
  int jhi = (b == 0) ? bb1 : (b == 1) ? bb2 : N_NODES;
  int len = jhi - jlo;
  int wlo = bnd32(jlo, jhi, len, q, Qb);
  int whi = bnd32(jlo, jhi, len, q + 1, Qb);
  if (wlo >= whi) return;   // fin skips empty slices with the same test

  int wave = threadIdx.x >> 6, lane = threadIdx.x & 63;
  int l15 = lane & 15, lk = lane >> 4;
  int row0 = blockIdx.x * 256 + wave * 64;   // this wave's 64 rows
  float elp[4], eln[4];
  const unsigned char* mr0;
  const unsigned char* mr1;
  const unsigned char* mr2;
  const unsigned char* mr3;
  {
    const unsigned char* mbase = maskB + (size_t)b * MASK_BSTRIDE;
#pragma unroll
    for (int rg = 0; rg < 4; ++rg) {
      int ip = row0 + rg * 16 + l15;
      elp[rg] = elpA[sidx * N_NODES + ip];
      eln[rg] = elnA[sidx * N_NODES + ip];
    }
    mr0 = mbase + (size_t)(row0 + 0 * 16 + l15) * MASK_BYTES;
    mr1 = mbase + (size_t)(row0 + 1 * 16 + l15) * MASK_BYTES;
    mr2 = mbase + (size_t)(row0 + 2 * 16 + l15) * MASK_BYTES;
    mr3 = mbase + (size_t)(row0 + 3 * 16 + l15) * MASK_BYTES;
  }
  const float* erpB = erpA + sidx * N_NODES;
  const float* ernB = ernA + sidx * N_NODES;
  const bf16* gPl = gP + (size_t)(colbase + l15) * 8;
  bf16x8 ones;
#pragma unroll
  for (int e = 0; e < 8; ++e) ones[e] = (bf16)1.0f;
  f32x4 acc[4][4] = {};
  f32x4 accl[4] = {};

  Stream s;
  load_stream<C>(s, wlo + lk * 8, erpB, ernB, mr0, mr1, mr2, mr3, gPl);
  for (int jt = wlo; jt < whi; jt += 32) {
    Stream cur = s;
    int nxt = jt + 32;
    if (nxt < whi) load_stream<C>(s, nxt + lk * 8, erpB, ernB, mr0, mr1, mr2, mr3, gPl);
    float pv[8] = { cur.p0.x, cur.p0.y, cur.p0.z, cur.p0.w, cur.p1.x, cur.p1.y, cur.p1.z, cur.p1.w };
    float nv[8] = { cur.n0.x, cur.n0.y, cur.n0.z, cur.n0.w, cur.n1.x, cur.n1.y, cur.n1.z, cur.n1.w };
#pragma unroll
    for (int rg = 0; rg < 4; ++rg) {
      unsigned int mb = (rg == 0) ? cur.m0 : (rg == 1) ? cur.m1 : (rg == 2) ? cur.m2 : cur.m3;
      bf16x8 a8;
#pragma unroll
      for (int e = 0; e < 8; ++e) {
        float z = elp[rg] * pv[e];
        float w = eln[rg] * nv[e];
        float p = (z >= 1.f) ? z : w;
        p = ((mb >> e) & 1u) ? p : 0.f;
        a8[e] = (bf16)p;
      }
      acc[rg][0] = __builtin_amdgcn_mfma_f32_16x16x32_bf16(a8, cur.b0, acc[rg][0], 0, 0, 0);
      acc[rg][1] = __builtin_amdgcn_mfma_f32_16x16x32_bf16(a8, cur.b1, acc[rg][1], 0, 0, 0);
      acc[rg][2] = __builtin_amdgcn_mfma_f32_16x16x32_bf16(a8, cur.b2, acc[rg][2], 0, 0, 0);
      acc[rg][3] = __builtin_amdgcn_mfma_f32_16x16x32_bf16(a8, cur.b3, acc[rg][3], 0, 0, 0);
      accl[rg] = __builtin_amdgcn_mfma_f32_16x16x32_bf16(a8, ones, accl[rg], 0, 0, 0);
    }
  }
  int slot = (b == 0) ? (c * QS + q) : (L1 ? (36 + (c - 6)) : (24 + (c - 4)));
  float* ap = accP + ((size_t)slot * N_NODES + row0) * 64;
#pragma unroll
  for (int rg = 0; rg < 4; ++rg)
#pragma unroll
    for (int nf = 0; nf < 4; ++nf)
#pragma unroll
      for (int r = 0; r < 4; ++r)
        ap[(rg * 16 + lk * 4 + r) * 64 + nf * 16 + l15] = acc[rg][nf][r];
  if (l15 == 0) {
#pragma unroll
    for (int rg = 0; rg < 4; ++rg)
#pragma unroll
      for (int r = 0; r < 4; ++r)
        lP[(size_t)slot * N_NODES + row0 + rg * 16 + lk * 4 + r] = accl[rg][r];
  }
}

// ---------------------------------------------------------------- finalize layer 1: sum slices, /l (or gmean), ELU
__global__ __launch_bounds__(256) void fin1_kernel(
    const float* __restrict__ accP, const float* __restrict__ lP,
    const float* __restrict__ gm, const int* __restrict__ dnum, const int* __restrict__ snum,
    bf16* __restrict__ out1) {
  int t = blockIdx.x * 256 + threadIdx.x;
  int i = t / (C1 / 8), f0 = (t - i * (C1 / 8)) * 8;
  int c = f0 >> 6;
  int b = c / 6;
  int dn = dnum[0], sn = snum[0];
  int bb1 = N_NODES - sn - dn, bb2 = N_NODES - dn;
  int jlo = (b == 0) ? 0 : (b == 1) ? bb1 : bb2;
  int jhi = (b == 0) ? bb1 : (b == 1) ? bb2 : N_NODES;
  int len = jhi - jlo;
  int Qb = (b == 0) ? QS : 1;
  float l = 0.f;
  float a[8] = {0.f,0.f,0.f,0.f,0.f,0.f,0.f,0.f};
  if (len > 0) {
    for (int q = 0; q < Qb; ++q) {
      if (bnd32(jlo, jhi, len, q, Qb) >= bnd32(jlo, jhi, len, q + 1, Qb)) continue;
      int slot = (b == 0) ? (c * QS + q) : (36 + (c - 6));
      l += lP[(size_t)slot * N_NODES + i];
      const float* ap = &accP[((size_t)slot * N_NODES + i) * 64 + (f0 & 63)];
      f32x4 v0 = *(const f32x4*)ap, v1 = *(const f32x4*)(ap + 4);
#pragma unroll
      for (int e = 0; e < 4; ++e) { a[e] += v0[e]; a[e + 4] += v1[e]; }
    }
  }
  float inv = (l > 0.f) ? 1.f / l : 0.f;
  bf16x8 o;
#pragma unroll
  for (int e = 0; e < 8; ++e) {
    float v = (l > 0.f) ? a[e] * inv : gm[f0 + e];
    v = (v > 0.f) ? v : (__expf(v) - 1.f);   // ELU
    o[e] = (bf16)v;
  }
  *(bf16x8*)&out1[(size_t)i * C1 + f0] = o;
}

// ---------------------------------------------------------------- finalize layer 2: sum slices, /l (or gmean), +residual -> fused
__global__ __launch_bounds__(256) void fin2_kernel(
    const float* __restrict__ accP, const float* __restrict__ lP,
    const float* __restrict__ gm, const float* __restrict__ feat,
    const int* __restrict__ dnum, const int* __restrict__ snum,
    bf16* __restrict__ fused) {
  int t = blockIdx.x * 256 + threadIdx.x;
  int i = t / (C2 / 8), f0 = (t - i * (C2 / 8)) * 8;
  int b = f0 >> 8;
  int fi = f0 & 255;
  int fc = (f0 >> 6) & 3;
  int c = b * 4 + fc;
  int dn = dnum[0], sn = snum[0];
  int bb1 = N_NODES - sn - dn, bb2 = N_NODES - dn;
  int jlo = (b == 0) ? 0 : (b == 1) ? bb1 : bb2;
  int jhi = (b == 0) ? bb1 : (b == 1) ? bb2 : N_NODES;
  int len = jhi - jlo;
  int Qb = (b == 0) ? QS : 1;
  float l = 0.f;
  float a[8] = {0.f,0.f,0.f,0.f,0.f,0.f,0.f,0.f};
  if (len > 0) {
    for (int q = 0; q < Qb; ++q) {
      if (bnd32(jlo, jhi, len, q, Qb) >= bnd32(jlo, jhi, len, q + 1, Qb)) continue;
      int slot = (b == 0) ? (c * QS + q) : (24 + (c - 4));
      l += lP[(size_t)slot * N_NODES + i];
      const float* ap = &accP[((size_t)slot * N_NODES + i) * 64 + (f0 & 63)];
      f32x4 v0 = *(const f32x4*)ap, v1 = *(const f32x4*)(ap + 4);
#pragma unroll
      for (int e = 0; e < 4; ++e) { a[e] += v0[e]; a[e + 4] += v1[e]; }
    }
  }
  float inv = (l > 0.f) ? 1.f / l : 0.f;
  bf16x8 o;
#pragma unroll
  for (int e = 0; e < 8; ++e) {
    float v = (l > 0.f) ? a[e] * inv : gm[f0 + e];
    v += feat[(size_t)i * D_IN + fi + e];
    o[e] = (bf16)v;
  }
  *(bf16x8*)&fused[(size_t)i * C2 + (2 - b) * D_IN + fi] = o;
}

// ---------------------------------------------------------------- launch
extern "C" void kernel_launch(void* const* d_in, const int* in_sizes, int n_in,
                              void* d_out, int out_size, void* d_ws, size_t ws_size,
                              hipStream_t stream) {
  (void)in_sizes; (void)n_in; (void)out_size; (void)ws_size;
  const float* feature = (const float*)d_in[0];
  const int*   adj     = (const int*)d_in[1];
  const int*   dnum    = (const int*)d_in[2];
  const int*   snum    = (const int*)d_in[3];
  const float* W1s = (const float*)d_in[4];  const float* a1s = (const float*)d_in[5];
  const float* W2s = (const float*)d_in[6];  const float* a2s = (const float*)d_in[7];
  const float* W1e = (const float*)d_in[8];  const float* a1e = (const float*)d_in[9];
  const float* W2e = (const float*)d_in[10]; const float* a2e = (const float*)d_in[11];
  const float* W1d = (const float*)d_in[12]; const float* a1d = (const float*)d_in[13];
  const float* W2d = (const float*)d_in[14]; const float* a2d = (const float*)d_in[15];
  const float* fW  = (const float*)d_in[16]; const float* fB  = (const float*)d_in[17];
  const float* w0  = (const float*)d_in[18]; const float* b0  = (const float*)d_in[19];
  const float* w1  = (const float*)d_in[20]; const float* b1  = (const float*)d_in[21];
  const float* w2  = (const float*)d_in[22]; const float* b2  = (const float*)d_in[23];

  char* ws = (char*)d_ws;
  size_t off = 0;
  auto alloc = [&](size_t bytes) { void* p = ws + off; off += (bytes + 255) & ~(size_t)255; return p; };

  unsigned long long* maskU = (unsigned long long*)alloc(3 * (size_t)N_NODES * MASK_ULL * 8);
  bf16* fbf   = (bf16*)alloc((size_t)N_NODES * D_IN * 2);
  bf16* w1b0  = (bf16*)alloc(HIDDEN * D_IN * 2);
  bf16* w1b1  = (bf16*)alloc(HIDDEN * D_IN * 2);
  bf16* w1b2  = (bf16*)alloc(HIDDEN * D_IN * 2);
  bf16* w2b0  = (bf16*)alloc(D_IN * HIDDEN * 2);
  bf16* w2b1  = (bf16*)alloc(D_IN * HIDDEN * 2);
  bf16* w2b2  = (bf16*)alloc(D_IN * HIDDEN * 2);
  bf16* wfusb = (bf16*)alloc(D_IN * C2 * 2);
  bf16* wf0b  = (bf16*)alloc(HIDDEN * D_IN * 2);
  bf16* wf1b  = (bf16*)alloc(HIDDEN * HIDDEN * 2);
  bf16* wf2b  = (bf16*)alloc(D_IN * HIDDEN * 2);
  bf16* g1    = (bf16*)alloc((size_t)N_NODES * C1 * 2);
  bf16* gP1   = (bf16*)alloc((size_t)N_NODES * C1 * 2);
  bf16* out1  = (bf16*)alloc((size_t)N_NODES * C1 * 2);
  bf16* g2    = (bf16*)alloc((size_t)N_NODES * C2 * 2);
  bf16* gP2   = (bf16*)alloc((size_t)N_NODES * C2 * 2);
  bf16* fusedB= (bf16*)alloc((size_t)N_NODES * C2 * 2);
  bf16* h0    = (bf16*)alloc((size_t)N_NODES * D_IN * 2);
  bf16* h1    = (bf16*)alloc((size_t)N_NODES * HIDDEN * 2);
  bf16* h2    = (bf16*)alloc((size_t)N_NODES * HIDDEN * 2);
  float* elp1 = (float*)alloc(18 * N_NODES * 4);
  float* eln1 = (float*)alloc(18 * N_NODES * 4);
  float* erp1 = (float*)alloc(18 * N_NODES * 4);
  float* ern1 = (float*)alloc(18 * N_NODES * 4);
  float* elp2 = (float*)alloc(3 * N_NODES * 4);
  float* eln2 = (float*)alloc(3 * N_NODES * 4);
  float* erp2 = (float*)alloc(3 * N_NODES * 4);
  float* ern2 = (float*)alloc(3 * N_NODES * 4);
  // partial buffers: att1 uses 48 slots (6 sent x6 + 12), att2 uses 32 (4x6 + 8) -> union 48
  float* accU = (float*)alloc((size_t)48 * N_NODES * 64 * 4);  // 37.7 MB
  float* lU   = (float*)alloc((size_t)48 * N_NODES * 4);
  // zero-initialized region: colmeans only
  size_t zoff = off;
  float* gm1  = (float*)alloc(C1 * 4);
  float* gm2  = (float*)alloc(C2 * 4);
  size_t zbytes = off - zoff;
  const unsigned char* maskBytes = (const unsigned char*)maskU;

  hipMemsetAsync(ws + zoff, 0, zbytes, stream);

  // 1) casts
  CastArgs ca;
  {
    const float* srcs[11] = { feature, W1s, W1e, W1d, W2s, W2e, W2d, fW, w0, w1, w2 };
    bf16* dsts[11] = { fbf, w1b0, w1b1, w1b2, w2b0, w2b1, w2b2, wfusb, wf0b, wf1b, wf2b };
    int counts[11] = { N_NODES*D_IN, HIDDEN*D_IN, HIDDEN*D_IN, HIDDEN*D_IN,
                       D_IN*HIDDEN, D_IN*HIDDEN, D_IN*HIDDEN, D_IN*C2,
                       HIDDEN*D_IN, HIDDEN*HIDDEN, D_IN*HIDDEN };
    int cum = 0;
    for (int k = 0; k < 11; ++k) { ca.src[k] = srcs[k]; ca.dst[k] = dsts[k]; ca.cum4[k] = cum; cum += counts[k] / 4; }
    ca.cum4[11] = cum;
    cast_all_kernel<<<cum / 256, 256, 0, stream>>>(ca);
  }
  // 2) pack adjacency bits (3 per-branch masks, range folded in)
  pack_adj_kernel<<<N_NODES, 256, 0, stream>>>(adj, maskU, dnum, snum);
  // 3) g1 = f @ W1^T (3 branches via z)
  gemm64_kernel<false,false,false,false><<<dim3(48,6,3), 256, 0, stream>>>(
      fbf, D_IN, 0, w1b0, w1b1, w1b2, D_IN, g1, C1, HIDDEN, D_IN, nullptr, nullptr);
  // 4) pack g1 -> gP1 (+colmean)
  pack_kernel<C1><<<dim3(48,18), 256, 0, stream>>>(g1, gP1, gm1);
  // 5) exp factors layer1
  head_proj_kernel<HEADS, NH1><<<dim3(192,18), 256, 0, stream>>>(g1, C1, a1s, a1e, a1d, elp1, eln1, erp1, ern1);
  // 6) attention 1 partials (64 rows/wave)
  att_kernel<true><<<dim3(12, 18, QS), 256, 0, stream>>>(gP1, elp1, eln1, erp1, ern1, maskBytes, dnum, snum, accU, lU);
  // 6b) finalize 1 (+ELU)
  fin1_kernel<<<N_NODES * (C1 / 8) / 256, 256, 0, stream>>>(accU, lU, gm1, dnum, snum, out1);
  // 7) g2 = out1 @ W2^T per branch
  gemm64_kernel<false,false,false,false><<<dim3(48,4,3), 256, 0, stream>>>(
      out1, C1, HIDDEN, w2b0, w2b1, w2b2, HIDDEN, g2, C2, D_IN, HIDDEN, nullptr, nullptr);
  // 8) pack g2 -> gP2 (+colmean)
  pack_kernel<C2><<<dim3(48,12), 256, 0, stream>>>(g2, gP2, gm2);
  // 9) exp factors layer2
  head_proj_kernel<1, D_IN><<<dim3(192,3), 256, 0, stream>>>(g2, C2, a2s, a2e, a2d, elp2, eln2, erp2, ern2);
  // 10) attention 2 partials
  att_kernel<false><<<dim3(12, 12, QS), 256, 0, stream>>>(gP2, elp2, eln2, erp2, ern2, maskBytes, dnum, snum, accU, lU);
  // 10b) finalize 2 (+residual, writes fused [doc,sect,sent])
  fin2_kernel<<<N_NODES * (C2 / 8) / 256, 256, 0, stream>>>(accU, lU, gm2, feature, dnum, snum, fusedB);
  // 11) fusion: h0 = leaky(fused @ fW^T + fB)
  gemm64_kernel<true,true,false,false><<<dim3(48,4,1), 256, 0, stream>>>(
      fusedB, C2, 0, wfusb, wfusb, wfusb, C2, h0, D_IN, 0, C2, fB, nullptr);
  // 12) ffn0: h1 = leaky(h0 @ w0^T + b0)
  gemm64_kernel<true,true,false,false><<<dim3(48,6,1), 256, 0, stream>>>(
      h0, D_IN, 0, wf0b, wf0b, wf0b, D_IN, h1, HIDDEN, 0, D_IN, b0, nullptr);
  // 13) ffn1: h2 = leaky(h1 @ w1^T + b1)
  gemm64_kernel<true,true,false,false><<<dim3(48,6,1), 256, 0, stream>>>(
      h1, HIDDEN, 0, wf1b, wf1b, wf1b, HIDDEN, h2, HIDDEN, 0, HIDDEN, b1, nullptr);
  // 14) ffn2: out = leaky(h2 @ w2^T + b2) + f   (fp32 out)
  gemm64_kernel<true,true,true,true><<<dim3(48,4,1), 256, 0, stream>>>(
      h2, HIDDEN, 0, wf2b, wf2b, wf2b, HIDDEN, d_out, D_IN, 0, HIDDEN, b2, feature);
}

// Round 7
// 282.316 us; speedup vs baseline: 1.1370x; 1.0112x over previous
//
#include <hip/hip_runtime.h>
#include <stdint.h>

#define N_NODES 3072
#define D_IN    256
#define HIDDEN  384
#define HEADS   6
#define NH1     64
#define C1      1152   // 3*HIDDEN
#define C2      768    // 3*D_IN
#define MASK_ULL   48  // 3072/64 per row
#define MASK_BYTES 384 // 3072/8 per row
#define MASK_BSTRIDE ((size_t)N_NODES * MASK_BYTES)  // per-branch mask stride (bytes)
#define QS      6      // j-splits for the sent branch (sect/doc get 1)
#define LOG2E   1.4426950408889634f

typedef __bf16 bf16;
typedef __bf16 bf16x8 __attribute__((ext_vector_type(8)));
typedef __bf16 bf16x4 __attribute__((ext_vector_type(4)));
typedef float  f32x4  __attribute__((ext_vector_type(4)));

__device__ __forceinline__ void atomAddF(float* p, float v) {
  __hip_atomic_fetch_add(p, v, __ATOMIC_RELAXED, __HIP_MEMORY_SCOPE_AGENT);
}
__device__ __forceinline__ float fexp2(float x) {   // D = 2^S0
  float r; asm("v_exp_f32 %0, %1" : "=v"(r) : "v"(x)); return r;
}
// 32-aligned chunk boundary: q in [0,Qb]; B(0) floors jlo, B(Qb) ceils jhi.
__device__ __forceinline__ int bnd32(int jlo, int jhi, int len, int q, int Qb) {
  return (q >= Qb) ? ((jhi + 31) & ~31) : ((jlo + (len * q) / Qb) & ~31);
}

// ---------------------------------------------------------------- merged: cast fp32->bf16 + adj bitmask pack
struct CastArgs {
  const float* src[11];
  bf16*        dst[11];
  int          cum4[12];
  int          castN;     // # cast blocks; blocks beyond do adj rows
};

__global__ __launch_bounds__(256) void prep_kernel(CastArgs A,
                                                   const int* __restrict__ adj,
                                                   unsigned long long* __restrict__ maskU,
                                                   const int* __restrict__ dnum,
                                                   const int* __restrict__ snum) {
  if ((int)blockIdx.x < A.castN) {
    int g = blockIdx.x * 256 + threadIdx.x;
    int j = 0;
#pragma unroll
    for (int k = 1; k < 11; ++k) j += (g >= A.cum4[k]);
    int e = (g - A.cum4[j]) * 4;
    float4 v = *(const float4*)(A.src[j] + e);
    bf16x4 o = { (bf16)v.x, (bf16)v.y, (bf16)v.z, (bf16)v.w };
    *(bf16x4*)(A.dst[j] + e) = o;
    return;
  }
  int dn = dnum[0], sn = snum[0];
  int bb1 = N_NODES - sn - dn, bb2 = N_NODES - dn;
  int row = blockIdx.x - A.castN;
  const int* ar = adj + (size_t)row * N_NODES;
  int lane = threadIdx.x & 63, wave = threadIdx.x >> 6;
#pragma unroll
  for (int it = 0; it < N_NODES / 256; ++it) {
    int j = it * 256 + wave * 64 + lane;
    bool a = ar[j] != 0;
    unsigned long long m0 = __ballot(a && (j < bb1));
    unsigned long long m1 = __ballot(a && (j >= bb1) && (j < bb2));
    unsigned long long m2 = __ballot(a && (j >= bb2));
    if (lane == 0) {
      size_t o = (size_t)row * MASK_ULL + it * 4 + wave;
      maskU[o] = m0;
      maskU[o + (size_t)N_NODES * MASK_ULL] = m1;
      maskU[o + 2 * (size_t)N_NODES * MASK_ULL] = m2;
    }
  }
}

// ---------------------------------------------------------------- pack g[j][f] -> gP[j/8][f][8] + column means (fused)
template<int C>
__global__ __launch_bounds__(256) void pack_kernel(const bf16* __restrict__ src,
                                                   bf16* __restrict__ dst,
                                                   float* __restrict__ gm) {
  __shared__ bf16 t[64][72];
  int j0 = blockIdx.x * 64, f0 = blockIdx.y * 64;
  int rr = threadIdx.x >> 4;
  int cc = (threadIdx.x & 15) * 4;
#pragma unroll
  for (int p = 0; p < 4; ++p) {
    int r = p * 16 + rr;
    *(bf16x4*)&t[r][cc] = *(const bf16x4*)&src[(size_t)(j0 + r) * C + f0 + cc];
  }
  __syncthreads();
  int f = threadIdx.x & 63, g = threadIdx.x >> 6;
#pragma unroll
  for (int q = 0; q < 2; ++q) {
    int p = g * 2 + q;
    bf16x8 v = { t[p*8+0][f], t[p*8+1][f], t[p*8+2][f], t[p*8+3][f],
                 t[p*8+4][f], t[p*8+5][f], t[p*8+6][f], t[p*8+7][f] };
    *(bf16x8*)&dst[ ((size_t)((j0 >> 3) + p) * C + f0 + f) * 8 ] = v;
  }
  // fused column-mean partial (tile already staged)
  float s = 0.f;
#pragma unroll
  for (int k = 0; k < 16; ++k) s += (float)t[g * 16 + k][f];
  atomAddF(&gm[f0 + f], s * (1.0f / N_NODES));
}

// ---------------------------------------------------------------- head projections -> exp-factor arrays
template<int NCPB, int NH>
__global__ __launch_bounds__(256) void head_proj_kernel(
    const bf16* __restrict__ g, int ldg,
    const float* __restrict__ a0, const float* __restrict__ a1, const float* __restrict__ a2,
    float* __restrict__ elp, float* __restrict__ eln,
    float* __restrict__ erp, float* __restrict__ ern) {
  int c = blockIdx.y;
  int i = blockIdx.x * 16 + (threadIdx.x >> 4);
  int b = c / NCPB;
  const float* a = (b == 0) ? a0 : (b == 1) ? a1 : a2;
  int f0 = (threadIdx.x & 15) * (NH / 16);
  const bf16* gr = g + (size_t)i * ldg + c * NH + f0;
  float accl = 0.f, accr = 0.f;
#pragma unroll
  for (int k = 0; k < NH / 16; k += 4) {
    bf16x4 v = *(const bf16x4*)&gr[k];
#pragma unroll
    for (int e = 0; e < 4; ++e) {
      float gv = (float)v[e];
      accl += gv * a[f0 + k + e];
      accr += gv * a[NH + f0 + k + e];
    }
  }
#pragma unroll
  for (int m = 1; m < 16; m <<= 1) {
    accl += __shfl_xor(accl, m, 64);
    accr += __shfl_xor(accr, m, 64);
  }
  if ((threadIdx.x & 15) == 0) {
    int o = c * N_NODES + i;
    elp[o] = fexp2(accl * LOG2E);
    eln[o] = fexp2(0.2f * accl * LOG2E);
    erp[o] = fexp2(accr * LOG2E);
    ern[o] = fexp2(0.2f * accr * LOG2E);
  }
}

// ---------------------------------------------------------------- GEMM 64x64 tile, single-barrier LDS double-buffer
template<bool BIAS, bool LEAKY, bool RES, bool F32OUT>
__global__ __launch_bounds__(256) void gemm64_kernel(
    const bf16* __restrict__ A, int lda, int aZoff,
    const bf16* __restrict__ B0, const bf16* __restrict__ B1, const bf16* __restrict__ B2,
    int ldb, void* __restrict__ Cout, int ldc, int cZoff, int K,
    const float* __restrict__ bias, const float* __restrict__ res) {
  __shared__ bf16 As[2 * 64 * 64];
  __shared__ bf16 Bs[2 * 64 * 64];
  int z = blockIdx.z;
  const bf16* Ab = A + (size_t)z * aZoff;
  const bf16* Bb = (z == 0) ? B0 : (z == 1) ? B1 : B2;
  int m0 = blockIdx.x * 64, n0 = blockIdx.y * 64;
  int tid = threadIdx.x;
  int lane = tid & 63, wave = tid >> 6;
  int wm = wave >> 1, wn = wave & 1;
  int l15 = lane & 15, lk = lane >> 4;
  // staging coordinates (2 units per matrix per thread)
  int r0 = tid >> 3, p0 = tid & 7, q0 = p0 ^ (r0 & 7);
  int r1 = (256 + tid) >> 3, p1 = tid & 7, q1 = p1 ^ (r1 & 7);
  bf16x8 ra0, ra1, rb0, rb1;
  auto gload = [&](int kt) {
    const bf16* ab = Ab + (size_t)kt * 64;
    const bf16* bb = Bb + (size_t)kt * 64;
    ra0 = *(const bf16x8*)&ab[(size_t)(m0 + r0) * lda + q0 * 8];
    ra1 = *(const bf16x8*)&ab[(size_t)(m0 + r1) * lda + q1 * 8];
    rb0 = *(const bf16x8*)&bb[(size_t)(n0 + r0) * ldb + q0 * 8];
    rb1 = *(const bf16x8*)&bb[(size_t)(n0 + r1) * ldb + q1 * 8];
  };
  auto sstore = [&](int buf) {
    bf16* as = As + buf * 4096;
    bf16* bs = Bs + buf * 4096;
    *(bf16x8*)&as[r0 * 64 + p0 * 8] = ra0;
    *(bf16x8*)&as[r1 * 64 + p1 * 8] = ra1;
    *(bf16x8*)&bs[r0 * 64 + p0 * 8] = rb0;
    *(bf16x8*)&bs[r1 * 64 + p1 * 8] = rb1;
  };
  f32x4 acc[2][2] = {};
  int nk = K >> 6;
  gload(0);
  sstore(0);
  __syncthreads();
  for (int kt = 0; kt < nk; ++kt) {
    bool more = (kt + 1) < nk;
    if (more) gload(kt + 1);               // issue early: latency hides under compute
    const bf16* as = As + (kt & 1) * 4096;
    const bf16* bs = Bs + (kt & 1) * 4096;
#pragma unroll
    for (int s = 0; s < 2; ++s) {
      bf16x8 af[2], bfr[2];
      int u = s * 4 + lk;
#pragma unroll
      for (int mi = 0; mi < 2; ++mi) {
        int r = wm * 32 + mi * 16 + l15;
        af[mi] = *(const bf16x8*)&as[r * 64 + (u ^ (r & 7)) * 8];
      }
#pragma unroll
      for (int ni = 0; ni < 2; ++ni) {
        int r = wn * 32 + ni * 16 + l15;
        bfr[ni] = *(const bf16x8*)&bs[r * 64 + (u ^ (r & 7)) * 8];
      }
#pragma unroll
      for (int mi = 0; mi < 2; ++mi)
#pragma unroll
        for (int ni = 0; ni < 2; ++ni)
          acc[mi][ni] = __builtin_amdgcn_mfma_f32_16x16x32_bf16(af[mi], bfr[ni], acc[mi][ni], 0, 0, 0);
    }
    if (more) sstore((kt + 1) & 1);        // write other buffer; readers of it sync below
    __syncthreads();
  }
#pragma unroll
  for (int mi = 0; mi < 2; ++mi)
#pragma unroll
    for (int ni = 0; ni < 2; ++ni)
#pragma unroll
      for (int r = 0; r < 4; ++r) {
        int i = m0 + wm * 32 + mi * 16 + lk * 4 + r;
        int col = z * cZoff + n0 + wn * 32 + ni * 16 + l15;
        float v = acc[mi][ni][r];
        if (BIAS) v += bias[col];
        if (LEAKY) v = (v >= 0.f) ? v : 0.01f * v;
        if (RES) v += res[(size_t)i * ldc + col];
        if (F32OUT) ((float*)Cout)[(size_t)i * ldc + col] = v;
        else        ((bf16*)Cout)[(size_t)i * ldc + col] = (bf16)v;
      }
}

// ---------------------------------------------------------------- attention: 64 rows x 64 cols per WAVE, ping-pong prefetch
struct Stream {
  float4 p0, p1, n0, n1;
  unsigned int m0, m1, m2, m3;
  bf16x8 b0, b1, b2, b3;
};

template<int C>
__device__ __forceinline__ void load_stream(
    Stream& s, int jb,
    const float* __restrict__ erpB, const float* __restrict__ ernB,
    const unsigned char* mr0, const unsigned char* mr1,
    const unsigned char* mr2, const unsigned char* mr3,
    const bf16* __restrict__ gPl) {
  s.p0 = *(const float4*)&erpB[jb];
  s.p1 = *(const float4*)&erpB[jb + 4];
  s.n0 = *(const float4*)&ernB[jb];
  s.n1 = *(const float4*)&ernB[jb + 4];
  int mo = jb >> 3;
  s.m0 = mr0[mo]; s.m1 = mr1[mo]; s.m2 = mr2[mo]; s.m3 = mr3[mo];
  const bf16* gp = gPl + (size_t)mo * C * 8;
  s.b0 = *(const bf16x8*)(gp + 0);
  s.b1 = *(const bf16x8*)(gp + 128);
  s.b2 = *(const bf16x8*)(gp + 256);
  s.b3 = *(const bf16x8*)(gp + 384);
}

template<bool L1>
__global__ __launch_bounds__(256, 2) void att_kernel(
    const bf16* __restrict__ gP,
    const float* __restrict__ elpA, const float* __restrict__ elnA,
    const float* __restrict__ erpA, const float* __restrict__ ernA,
    const unsigned char* __restrict__ maskB,
    const int* __restrict__ dnum, const int* __restrict__ snum,
    float* __restrict__ accP, float* __restrict__ lP) {
  constexpr int C = L1 ? C1 : C2;
  int c = blockIdx.y;
  int b = L1 ? (c / 6) : (c >> 2);
  int colbase = L1 ? c * 64 : (b * 256 + (c & 3) * 64);
  int sidx = L1 ? c : b;
  int q = blockIdx.z;
  int Qb = (b == 0) ? QS : 1;
  if (q >= Qb) return;
  int dn = dnum[0], sn = snum[0];
  int bb1 = N_NODES - sn - dn, bb2 = N_NODES - dn;
  int jlo = (b == 0) ? 0 : (b == 1) ? bb1 : bb2;
  int jhi = (b == 0) ? bb1 : (b == 1) ? bb2 : N_NODES;
  int len = jhi - jlo;
  int wlo = bnd32(jlo, jhi, len, q, Qb);
  int whi = bnd32(jlo, jhi, len, q + 1, Qb);
  if (wlo >= whi) return;   // fin skips empty slices with the same test

  int wave = threadIdx.x >> 6, lane = threadIdx.x & 63;
  int l15 = lane & 15, lk = lane >> 4;
  int row0 = blockIdx.x * 256 + wave * 64;   // this wave's 64 rows
  float elp[4], eln[4];
  const unsigned char* mr0;
  const unsigned char* mr1;
  const unsigned char* mr2;
  const unsigned char* mr3;
  {
    const unsigned char* mbase = maskB + (size_t)b * MASK_BSTRIDE;
#pragma unroll
    for (int rg = 0; rg < 4; ++rg) {
      int ip = row0 + rg * 16 + l15;
      elp[rg] = elpA[sidx * N_NODES + ip];
      eln[rg] = elnA[sidx * N_NODES + ip];
    }
    mr0 = mbase + (size_t)(row0 + 0 * 16 + l15) * MASK_BYTES;
    mr1 = mbase + (size_t)(row0 + 1 * 16 + l15) * MASK_BYTES;
    mr2 = mbase + (size_t)(row0 + 2 * 16 + l15) * MASK_BYTES;
    mr3 = mbase + (size_t)(row0 + 3 * 16 + l15) * MASK_BYTES;
  }
  const float* erpB = erpA + sidx * N_NODES;
  const float* ernB = ernA + sidx * N_NODES;
  const bf16* gPl = gP + (size_t)(colbase + l15) * 8;
  bf16x8 ones;
#pragma unroll
  for (int e = 0; e < 8; ++e) ones[e] = (bf16)1.0f;
  f32x4 acc[4][4] = {};
  f32x4 accl[4] = {};

  auto compute = [&](const Stream& cur) {
    float pv[8] = { cur.p0.x, cur.p0.y, cur.p0.z, cur.p0.w, cur.p1.x, cur.p1.y, cur.p1.z, cur.p1.w };
    float nv[8] = { cur.n0.x, cur.n0.y, cur.n0.z, cur.n0.w, cur.n1.x, cur.n1.y, cur.n1.z, cur.n1.w };
#pragma unroll
    for (int rg = 0; rg < 4; ++rg) {
      unsigned int mb = (rg == 0) ? cur.m0 : (rg == 1) ? cur.m1 : (rg == 2) ? cur.m2 : cur.m3;
      bf16x8 a8;
#pragma unroll
      for (int e = 0; e < 8; ++e) {
        float z = elp[rg] * pv[e];
        float w = eln[rg] * nv[e];
        float p = (z >= 1.f) ? z : w;
        p = ((mb >> e) & 1u) ? p : 0.f;
        a8[e] = (bf16)p;
      }
      acc[rg][0] = __builtin_amdgcn_mfma_f32_16x16x32_bf16(a8, cur.b0, acc[rg][0], 0, 0, 0);
      acc[rg][1] = __builtin_amdgcn_mfma_f32_16x16x32_bf16(a8, cur.b1, acc[rg][1], 0, 0, 0);
      acc[rg][2] = __builtin_amdgcn_mfma_f32_16x16x32_bf16(a8, cur.b2, acc[rg][2], 0, 0, 0);
      acc[rg][3] = __builtin_amdgcn_mfma_f32_16x16x32_bf16(a8, cur.b3, acc[rg][3], 0, 0, 0);
      accl[rg] = __builtin_amdgcn_mfma_f32_16x16x32_bf16(a8, ones, accl[rg], 0, 0, 0);
    }
  };

  // ping-pong software pipeline: two named Stream states, no copies
  Stream s0, s1;
  load_stream<C>(s0, wlo + lk * 8, erpB, ernB, mr0, mr1, mr2, mr3, gPl);
  int jt = wlo;
  while (true) {
    bool m1 = (jt + 32) < whi;
    if (m1) load_stream<C>(s1, jt + 32 + lk * 8, erpB, ernB, mr0, mr1, mr2, mr3, gPl);
    compute(s0);
    if (!m1) break;
    bool m2 = (jt + 64) < whi;
    if (m2) load_stream<C>(s0, jt + 64 + lk * 8, erpB, ernB, mr0, mr1, mr2, mr3, gPl);
    compute(s1);
    if (!m2) break;
    jt += 64;
  }

  int slot = (b == 0) ? (c * QS + q) : (L1 ? (36 + (c - 6)) : (24 + (c - 4)));
  float* ap = accP + ((size_t)slot * N_NODES + row0) * 64;
#pragma unroll
  for (int rg = 0; rg < 4; ++rg)
#pragma unroll
    for (int nf = 0; nf < 4; ++nf)
#pragma unroll
      for (int r = 0; r < 4; ++r)
        ap[(rg * 16 + lk * 4 + r) * 64 + nf * 16 + l15] = acc[rg][nf][r];
  if (l15 == 0) {
#pragma unroll
    for (int rg = 0; rg < 4; ++rg)
#pragma unroll
      for (int r = 0; r < 4; ++r)
        lP[(size_t)slot * N_NODES + row0 + rg * 16 + lk * 4 + r] = accl[rg][r];
  }
}

// ---------------------------------------------------------------- finalize layer 1: sum slices, /l (or gmean), ELU
__global__ __launch_bounds__(256) void fin1_kernel(
    const float* __restrict__ accP, const float* __restrict__ lP,
    const float* __restrict__ gm, const int* __restrict__ dnum, const int* __restrict__ snum,
    bf16* __restrict__ out1) {
  int t = blockIdx.x * 256 + threadIdx.x;
  int i = t / (C1 / 8), f0 = (t - i * (C1 / 8)) * 8;
  int c = f0 >> 6;
  int b = c / 6;
  int dn = dnum[0], sn = snum[0];
  int bb1 = N_NODES - sn - dn, bb2 = N_NODES - dn;
  int jlo = (b == 0) ? 0 : (b == 1) ? bb1 : bb2;
  int jhi = (b == 0) ? bb1 : (b == 1) ? bb2 : N_NODES;
  int len = jhi - jlo;
  int Qb = (b == 0) ? QS : 1;
  float l = 0.f;
  float a[8] = {0.f,0.f,0.f,0.f,0.f,0.f,0.f,0.f};
  if (len > 0) {
    for (int q = 0; q < Qb; ++q) {
      if (bnd32(jlo, jhi, len, q, Qb) >= bnd32(jlo, jhi, len, q + 1, Qb)) continue;
      int slot = (b == 0) ? (c * QS + q) : (36 + (c - 6));
      l += lP[(size_t)slot * N_NODES + i];
      const float* ap = &accP[((size_t)slot * N_NODES + i) * 64 + (f0 & 63)];
      f32x4 v0 = *(const f32x4*)ap, v1 = *(const f32x4*)(ap + 4);
#pragma unroll
      for (int e = 0; e < 4; ++e) { a[e] += v0[e]; a[e + 4] += v1[e]; }
    }
  }
  float inv = (l > 0.f) ? 1.f / l : 0.f;
  bf16x8 o;
#pragma unroll
  for (int e = 0; e < 8; ++e) {
    float v = (l > 0.f) ? a[e] * inv : gm[f0 + e];
    v = (v > 0.f) ? v : (__expf(v) - 1.f);   // ELU
    o[e] = (bf16)v;
  }
  *(bf16x8*)&out1[(size_t)i * C1 + f0] = o;
}

// ---------------------------------------------------------------- finalize layer 2: sum slices, /l (or gmean), +residual -> fused
__global__ __launch_bounds__(256) void fin2_kernel(
    const float* __restrict__ accP, const float* __restrict__ lP,
    const float* __restrict__ gm, const float* __restrict__ feat,
    const int* __restrict__ dnum, const int* __restrict__ snum,
    bf16* __restrict__ fused) {
  int t = blockIdx.x * 256 + threadIdx.x;
  int i = t / (C2 / 8), f0 = (t - i * (C2 / 8)) * 8;
  int b = f0 >> 8;
  int fi = f0 & 255;
  int fc = (f0 >> 6) & 3;
  int c = b * 4 + fc;
  int dn = dnum[0], sn = snum[0];
  int bb1 = N_NODES - sn - dn, bb2 = N_NODES - dn;
  int jlo = (b == 0) ? 0 : (b == 1) ? bb1 : bb2;
  int jhi = (b == 0) ? bb1 : (b == 1) ? bb2 : N_NODES;
  int len = jhi - jlo;
  int Qb = (b == 0) ? QS : 1;
  float l = 0.f;
  float a[8] = {0.f,0.f,0.f,0.f,0.f,0.f,0.f,0.f};
  if (len > 0) {
    for (int q = 0; q < Qb; ++q) {
      if (bnd32(jlo, jhi, len, q, Qb) >= bnd32(jlo, jhi, len, q + 1, Qb)) continue;
      int slot = (b == 0) ? (c * QS + q) : (24 + (c - 4));
      l += lP[(size_t)slot * N_NODES + i];
      const float* ap = &accP[((size_t)slot * N_NODES + i) * 64 + (f0 & 63)];
      f32x4 v0 = *(const f32x4*)ap, v1 = *(const f32x4*)(ap + 4);
#pragma unroll
      for (int e = 0; e < 4; ++e) { a[e] += v0[e]; a[e + 4] += v1[e]; }
    }
  }
  float inv = (l > 0.f) ? 1.f / l : 0.f;
  bf16x8 o;
#pragma unroll
  for (int e = 0; e < 8; ++e) {
    float v = (l > 0.f) ? a[e] * inv : gm[f0 + e];
    v += feat[(size_t)i * D_IN + fi + e];
    o[e] = (bf16)v;
  }
  *(bf16x8*)&fused[(size_t)i * C2 + (2 - b) * D_IN + fi] = o;
}

// ---------------------------------------------------------------- launch
extern "C" void kernel_launch(void* const* d_in, const int* in_sizes, int n_in,
                              void* d_out, int out_size, void* d_ws, size_t ws_size,
                              hipStream_t stream) {
  (void)in_sizes; (void)n_in; (void)out_size; (void)ws_size;
  const float* feature = (const float*)d_in[0];
  const int*   adj     = (const int*)d_in[1];
  const int*   dnum    = (const int*)d_in[2];
  const int*   snum    = (const int*)d_in[3];
  const float* W1s = (const float*)d_in[4];  const float* a1s = (const float*)d_in[5];
  const float* W2s = (const float*)d_in[6];  const float* a2s = (const float*)d_in[7];
  const float* W1e = (const float*)d_in[8];  const float* a1e = (const float*)d_in[9];
  const float* W2e = (const float*)d_in[10]; const float* a2e = (const float*)d_in[11];
  const float* W1d = (const float*)d_in[12]; const float* a1d = (const float*)d_in[13];
  const float* W2d = (const float*)d_in[14]; const float* a2d = (const float*)d_in[15];
  const float* fW  = (const float*)d_in[16]; const float* fB  = (const float*)d_in[17];
  const float* w0  = (const float*)d_in[18]; const float* b0  = (const float*)d_in[19];
  const float* w1  = (const float*)d_in[20]; const float* b1  = (const float*)d_in[21];
  const float* w2  = (const float*)d_in[22]; const float* b2  = (const float*)d_in[23];

  char* ws = (char*)d_ws;
  size_t off = 0;
  auto alloc = [&](size_t bytes) { void* p = ws + off; off += (bytes + 255) & ~(size_t)255; return p; };

  unsigned long long* maskU = (unsigned long long*)alloc(3 * (size_t)N_NODES * MASK_ULL * 8);
  bf16* fbf   = (bf16*)alloc((size_t)N_NODES * D_IN * 2);
  bf16* w1b0  = (bf16*)alloc(HIDDEN * D_IN * 2);
  bf16* w1b1  = (bf16*)alloc(HIDDEN * D_IN * 2);
  bf16* w1b2  = (bf16*)alloc(HIDDEN * D_IN * 2);
  bf16* w2b0  = (bf16*)alloc(D_IN * HIDDEN * 2);
  bf16* w2b1  = (bf16*)alloc(D_IN * HIDDEN * 2);
  bf16* w2b2  = (bf16*)alloc(D_IN * HIDDEN * 2);
  bf16* wfusb = (bf16*)alloc(D_IN * C2 * 2);
  bf16* wf0b  = (bf16*)alloc(HIDDEN * D_IN * 2);
  bf16* wf1b  = (bf16*)alloc(HIDDEN * HIDDEN * 2);
  bf16* wf2b  = (bf16*)alloc(D_IN * HIDDEN * 2);
  bf16* g1    = (bf16*)alloc((size_t)N_NODES * C1 * 2);
  bf16* gP1   = (bf16*)alloc((size_t)N_NODES * C1 * 2);
  bf16* out1  = (bf16*)alloc((size_t)N_NODES * C1 * 2);
  bf16* g2    = (bf16*)alloc((size_t)N_NODES * C2 * 2);
  bf16* gP2   = (bf16*)alloc((size_t)N_NODES * C2 * 2);
  bf16* fusedB= (bf16*)alloc((size_t)N_NODES * C2 * 2);
  bf16* h0    = (bf16*)alloc((size_t)N_NODES * D_IN * 2);
  bf16* h1    = (bf16*)alloc((size_t)N_NODES * HIDDEN * 2);
  bf16* h2    = (bf16*)alloc((size_t)N_NODES * HIDDEN * 2);
  float* elp1 = (float*)alloc(18 * N_NODES * 4);
  float* eln1 = (float*)alloc(18 * N_NODES * 4);
  float* erp1 = (float*)alloc(18 * N_NODES * 4);
  float* ern1 = (float*)alloc(18 * N_NODES * 4);
  float* elp2 = (float*)alloc(3 * N_NODES * 4);
  float* eln2 = (float*)alloc(3 * N_NODES * 4);
  float* erp2 = (float*)alloc(3 * N_NODES * 4);
  float* ern2 = (float*)alloc(3 * N_NODES * 4);
  // partial buffers: att1 uses 48 slots (6 sent x6 + 12), att2 uses 32 (4x6 + 8) -> union 48
  float* accU = (float*)alloc((size_t)48 * N_NODES * 64 * 4);  // 37.7 MB
  float* lU   = (float*)alloc((size_t)48 * N_NODES * 4);
  // zero-initialized region: colmeans only
  size_t zoff = off;
  float* gm1  = (float*)alloc(C1 * 4);
  float* gm2  = (float*)alloc(C2 * 4);
  size_t zbytes = off - zoff;
  const unsigned char* maskBytes = (const unsigned char*)maskU;

  hipMemsetAsync(ws + zoff, 0, zbytes, stream);

  // 1) casts + adjacency bitmask pack (merged)
  CastArgs ca;
  {
    const float* srcs[11] = { feature, W1s, W1e, W1d, W2s, W2e, W2d, fW, w0, w1, w2 };
    bf16* dsts[11] = { fbf, w1b0, w1b1, w1b2, w2b0, w2b1, w2b2, wfusb, wf0b, wf1b, wf2b };
    int counts[11] = { N_NODES*D_IN, HIDDEN*D_IN, HIDDEN*D_IN, HIDDEN*D_IN,
                       D_IN*HIDDEN, D_IN*HIDDEN, D_IN*HIDDEN, D_IN*C2,
                       HIDDEN*D_IN, HIDDEN*HIDDEN, D_IN*HIDDEN };
    int cum = 0;
    for (int k = 0; k < 11; ++k) { ca.src[k] = srcs[k]; ca.dst[k] = dsts[k]; ca.cum4[k] = cum; cum += counts[k] / 4; }
    ca.cum4[11] = cum;
    ca.castN = cum / 256;
    prep_kernel<<<ca.castN + N_NODES, 256, 0, stream>>>(ca, adj, maskU, dnum, snum);
  }
  // 2) g1 = f @ W1^T (3 branches via z)
  gemm64_kernel<false,false,false,false><<<dim3(48,6,3), 256, 0, stream>>>(
      fbf, D_IN, 0, w1b0, w1b1, w1b2, D_IN, g1, C1, HIDDEN, D_IN, nullptr, nullptr);
  // 3) pack g1 -> gP1 (+colmean)
  pack_kernel<C1><<<dim3(48,18), 256, 0, stream>>>(g1, gP1, gm1);
  // 4) exp factors layer1
  head_proj_kernel<HEADS, NH1><<<dim3(192,18), 256, 0, stream>>>(g1, C1, a1s, a1e, a1d, elp1, eln1, erp1, ern1);
  // 5) attention 1 partials (64 rows/wave, ping-pong prefetch)
  att_kernel<true><<<dim3(12, 18, QS), 256, 0, stream>>>(gP1, elp1, eln1, erp1, ern1, maskBytes, dnum, snum, accU, lU);
  // 5b) finalize 1 (+ELU)
  fin1_kernel<<<N_NODES * (C1 / 8) / 256, 256, 0, stream>>>(accU, lU, gm1, dnum, snum, out1);
  // 6) g2 = out1 @ W2^T per branch
  gemm64_kernel<false,false,false,false><<<dim3(48,4,3), 256, 0, stream>>>(
      out1, C1, HIDDEN, w2b0, w2b1, w2b2, HIDDEN, g2, C2, D_IN, HIDDEN, nullptr, nullptr);
  // 7) pack g2 -> gP2 (+colmean)
  pack_kernel<C2><<<dim3(48,12), 256, 0, stream>>>(g2, gP2, gm2);
  // 8) exp factors layer2
  head_proj_kernel<1, D_IN><<<dim3(192,3), 256, 0, stream>>>(g2, C2, a2s, a2e, a2d, elp2, eln2, erp2, ern2);
  // 9) attention 2 partials
  att_kernel<false><<<dim3(12, 12, QS), 256, 0, stream>>>(gP2, elp2, eln2, erp2, ern2, maskBytes, dnum, snum, accU, lU);
  // 9b) finalize 2 (+residual, writes fused [doc,sect,sent])
  fin2_kernel<<<N_NODES * (C2 / 8) / 256, 256, 0, stream>>>(accU, lU, gm2, feature, dnum, snum, fusedB);
  // 10) fusion: h0 = leaky(fused @ fW^T + fB)
  gemm64_kernel<true,true,false,false><<<dim3(48,4,1), 256, 0, stream>>>(
      fusedB, C2, 0, wfusb, wfusb, wfusb, C2, h0, D_IN, 0, C2, fB, nullptr);
  // 11) ffn0: h1 = leaky(h0 @ w0^T + b0)
  gemm64_kernel<true,true,false,false><<<dim3(48,6,1), 256, 0, stream>>>(
      h0, D_IN, 0, wf0b, wf0b, wf0b, D_IN, h1, HIDDEN, 0, D_IN, b0, nullptr);
  // 12) ffn1: h2 = leaky(h1 @ w1^T + b1)
  gemm64_kernel<true,true,false,false><<<dim3(48,6,1), 256, 0, stream>>>(
      h1, HIDDEN, 0, wf1b, wf1b, wf1b, HIDDEN, h2, HIDDEN, 0, HIDDEN, b1, nullptr);
  // 13) ffn2: out = leaky(h2 @ w2^T + b2) + f   (fp32 out)
  gemm64_kernel<true,true,true,true><<<dim3(48,4,1), 256, 0, stream>>>(
      h2, HIDDEN, 0, wf2b, wf2b, wf2b, HIDDEN, d_out, D_IN, 0, HIDDEN, b2, feature);
}